// Round 1
// baseline (876.109 us; speedup 1.0000x reference)
//
#include <hip/hip_runtime.h>

typedef float f4 __attribute__((ext_vector_type(4)));

#define EPSV 1e-5f

// ---------------------------------------------------------------------------
// Pass 0: find graph boundaries in the sorted batch vector.
// offsets[g] = first row index belonging to graph g; offsets[B] = N.
// Every entry of offsets[0..B] is written every launch (ws is re-poisoned).
// ---------------------------------------------------------------------------
template <typename IndexT>
__global__ void boundaries_k(const IndexT* __restrict__ batch,
                             const int* __restrict__ bsz,
                             int N, int* __restrict__ offsets) {
    int B = bsz[0];
    int i = blockIdx.x * blockDim.x + threadIdx.x;
    if (i >= N) return;
    int b    = (int)batch[i];
    int prev = (i == 0) ? -1 : (int)batch[i - 1];
    for (int g = prev + 1; g <= b; ++g) offsets[g] = i;
    if (i == N - 1) {
        for (int g = b + 1; g <= B; ++g) offsets[g] = N;
    }
}

// ---------------------------------------------------------------------------
// Main kernel: one block per graph (grid-stride over graphs).
// Pass A: accumulate sum and sum-of-squares over the graph's contiguous slab.
// Pass B: normalize; slab should still be L3-resident (128 MB active < 256 MB).
// C is hardcoded to 256 floats/row = 64 float4 per row.
// ---------------------------------------------------------------------------
__global__ __launch_bounds__(1024, 1) void graphnorm_k(
    const float* __restrict__ x, const float* __restrict__ w,
    const float* __restrict__ bias, const int* __restrict__ offsets,
    const int* __restrict__ bsz, float* __restrict__ out) {

    __shared__ float redS[16], redQ[16];
    __shared__ float sMean, sInv;

    const int B   = bsz[0];
    const int tid = threadIdx.x;

    // Stride 1024 is a multiple of 64, so each thread's channel-quad is fixed:
    const int cq = tid & 63;
    const f4 wv = ((const f4*)w)[cq];
    const f4 bv = ((const f4*)bias)[cq];

    for (int g = blockIdx.x; g < B; g += gridDim.x) {
        const int s   = offsets[g];
        const int e   = offsets[g + 1];
        const int cnt = e - s;
        const long long base = (long long)s * 256;
        const f4* __restrict__ xp = (const f4*)(x + base);
        const int n4 = cnt * 64;   // float4 elements in this graph's slab

        float sum = 0.f, sq = 0.f;
        for (int i = tid; i < n4; i += 1024) {
            f4 v = xp[i];
            sum += (v.x + v.y) + (v.z + v.w);
            sq  += (v.x * v.x + v.y * v.y) + (v.z * v.z + v.w * v.w);
        }

        // wave64 butterfly reduce
        for (int off = 32; off; off >>= 1) {
            sum += __shfl_down(sum, off, 64);
            sq  += __shfl_down(sq, off, 64);
        }
        if ((tid & 63) == 0) { redS[tid >> 6] = sum; redQ[tid >> 6] = sq; }
        __syncthreads();
        if (tid == 0) {
            float ts = 0.f, tq = 0.f;
#pragma unroll
            for (int k = 0; k < 16; ++k) { ts += redS[k]; tq += redQ[k]; }
            const float norm = fmaxf((float)cnt, 1.0f) * 256.0f;
            sMean = ts / norm;
            sInv  = rsqrtf(tq / norm + EPSV);
        }
        __syncthreads();
        const float mean = sMean;
        const float inv  = sInv;

        f4* op = (f4*)(out + base);
        for (int i = tid; i < n4; i += 1024) {
            f4 v = xp[i];                        // expected L3 hit
            f4 o = (v - mean) * inv * wv + bv;
            __builtin_nontemporal_store(o, &op[i]);
        }
        __syncthreads();   // keep waves in lockstep before redS/sMean reuse
    }
}

extern "C" void kernel_launch(void* const* d_in, const int* in_sizes, int n_in,
                              void* d_out, int out_size, void* d_ws, size_t ws_size,
                              hipStream_t stream) {
    const float* x  = (const float*)d_in[0];
    const float* w  = (const float*)d_in[1];
    const float* b  = (const float*)d_in[2];
    const int*   bs = (const int*)d_in[4];   // batch_size scalar (device)

    const int C = in_sizes[1];               // 256
    const int N = in_sizes[0] / C;           // 500000
    int* offsets = (int*)d_ws;               // (B+1) ints of scratch

    const int nblk = (N + 255) / 256;
    if (in_sizes[3] == 2 * N) {
        // harness delivered raw int64 words
        boundaries_k<long long><<<nblk, 256, 0, stream>>>(
            (const long long*)d_in[3], bs, N, offsets);
    } else {
        boundaries_k<int><<<nblk, 256, 0, stream>>>(
            (const int*)d_in[3], bs, N, offsets);
    }

    graphnorm_k<<<256, 1024, 0, stream>>>(x, w, b, offsets, bs, (float*)d_out);
}